// Round 2
// baseline (3105.456 us; speedup 1.0000x reference)
//
#include <hip/hip_runtime.h>
#include <hip/hip_bf16.h>

#define E_ 8
#define H_ 2048
#define D_ 4096
#define R_ 8
#define T_ 2048
#define TWO_D_ 8192
#define SCALE_ 2.0f
#define LDSK 40  // fallback-path padded LDS stride

typedef __attribute__((ext_vector_type(8))) short short8;
typedef __attribute__((ext_vector_type(4))) float f32x4;

__device__ __forceinline__ unsigned short f2bf(float f) {
  union { float f; unsigned u; } c; c.f = f;
  unsigned u = c.u + 0x7fffu + ((c.u >> 16) & 1u);  // RNE
  return (unsigned short)(u >> 16);
}
__device__ __forceinline__ float bf2f(unsigned short s) {
  union { unsigned u; float f; } c; c.u = ((unsigned)s) << 16;
  return c.f;
}

// async 16B global -> LDS (linear dest: wave-uniform base + lane*16)
__device__ __forceinline__ void gl16(const void* g, void* l) {
  __builtin_amdgcn_global_load_lds(
      (const __attribute__((address_space(1))) void*)g,
      (__attribute__((address_space(3))) void*)l, 16, 0, 0);
}

// ---------------- rank-8 projection: low[tok][r] = sum_i X[tok][i]*A[e][r][i]
template <int K, bool XBF16>
__global__ __launch_bounds__(256) void k_low(const void* __restrict__ Xv,
                                             const float* __restrict__ A,
                                             float* __restrict__ low) {
  int wave = (blockIdx.x * 256 + threadIdx.x) >> 6;
  int lane = threadIdx.x & 63;
  int e = wave >> 11;  // / T_
  const float* Ae = A + (long)e * R_ * K;
  float acc[R_] = {0.f,0.f,0.f,0.f,0.f,0.f,0.f,0.f};
  for (int it = 0; it < K / 256; ++it) {
    int i = it * 256 + lane * 4;
    float xv[4];
    if constexpr (!XBF16) {
      const float* x = (const float*)Xv + (long)wave * K;
      f32x4 v = *(const f32x4*)(x + i);
      xv[0]=v[0]; xv[1]=v[1]; xv[2]=v[2]; xv[3]=v[3];
    } else {
      const unsigned short* x = (const unsigned short*)Xv + (long)wave * K;
      ushort4 u = *(const ushort4*)(x + i);
      xv[0]=bf2f(u.x); xv[1]=bf2f(u.y); xv[2]=bf2f(u.z); xv[3]=bf2f(u.w);
    }
    #pragma unroll
    for (int r = 0; r < R_; ++r) {
      f32x4 a = *(const f32x4*)(Ae + r * K + i);
      acc[r] += xv[0]*a[0] + xv[1]*a[1] + xv[2]*a[2] + xv[3]*a[3];
    }
  }
  #pragma unroll
  for (int r = 0; r < R_; ++r) {
    float v = acc[r];
    #pragma unroll
    for (int off = 32; off > 0; off >>= 1) v += __shfl_xor(v, off);
    acc[r] = v;
  }
  if (lane == 0) {
    #pragma unroll
    for (int r = 0; r < R_; ++r) low[(long)wave * R_ + r] = acc[r];
  }
}

// ---------------- fp32 -> bf16 bulk conversion (grid-stride, 8 elems/thread)
__global__ __launch_bounds__(256) void k_f2bf(const float* __restrict__ src,
                                              unsigned short* __restrict__ dst,
                                              long n) {
  long i = ((long)blockIdx.x * 256 + threadIdx.x) * 8;
  long stride = (long)gridDim.x * 256 * 8;
  for (; i < n; i += stride) {
    f32x4 a = *(const f32x4*)(src + i);
    f32x4 b = *(const f32x4*)(src + i + 4);
    ushort4 lo, hi;
    lo.x=f2bf(a[0]); lo.y=f2bf(a[1]); lo.z=f2bf(a[2]); lo.w=f2bf(a[3]);
    hi.x=f2bf(b[0]); hi.y=f2bf(b[1]); hi.z=f2bf(b[2]); hi.w=f2bf(b[3]);
    *(ushort4*)(dst + i) = lo;
    *(ushort4*)(dst + i + 4) = hi;
  }
}

// ---------------- GEMM1 v2 (bf16 in, global_load_lds staging, swapped-operand MFMA)
// h = up*silu(gate); gate_up = x@Wgu^T + SCALE*low1@Bgu^T
__global__ __launch_bounds__(256, 2) void k_gemm1b(
    const unsigned short* __restrict__ Xb, const unsigned short* __restrict__ Wb,
    const float* __restrict__ Bgu, const float* __restrict__ low,
    unsigned short* __restrict__ Hout) {
  __shared__ __align__(16) unsigned short smem[3 * 128 * 32];
  unsigned short* sA  = smem;
  unsigned short* sBg = smem + 128 * 32;
  unsigned short* sBu = smem + 2 * 128 * 32;

  const int MT = T_ / 128, NT = D_ / 128;  // 16, 32
  int b = blockIdx.x;
  int cpx = (int)gridDim.x >> 3;
  int swz = (b & 7) * cpx + (b >> 3);     // bijective: grid % 8 == 0
  int e  = swz / (MT * NT);
  int r0 = swz % (MT * NT);
  int nt = r0 / MT, mt = r0 % MT;

  int tid = threadIdx.x, lane = tid & 63, w = tid >> 6;
  int wr = (w >> 1) * 64, wc = (w & 1) * 64;

  // staging chunks: chunk c (16B) -> LDS byte c*16; row=c>>2, col-chunk=c&3
  int cA = tid, cB = 256 + tid;
  int arA = cA >> 2, acA = (cA & 3) * 8;
  int arB = cB >> 2, acB = (cB & 3) * 8;
  const unsigned short* pA0 = Xb + ((long)(e * T_) + mt * 128 + arA) * H_ + acA;
  const unsigned short* pA1 = Xb + ((long)(e * T_) + mt * 128 + arB) * H_ + acB;
  const unsigned short* pG0 = Wb + ((long)e * TWO_D_ + nt * 128 + arA) * (long)H_ + acA;
  const unsigned short* pG1 = Wb + ((long)e * TWO_D_ + nt * 128 + arB) * (long)H_ + acB;
  const unsigned short* pU0 = pG0 + (long)D_ * H_;
  const unsigned short* pU1 = pG1 + (long)D_ * H_;
  unsigned short* lA0 = sA + cA * 8;  unsigned short* lA1 = sA + cB * 8;
  unsigned short* lG0 = sBg + cA * 8; unsigned short* lG1 = sBg + cB * 8;
  unsigned short* lU0 = sBu + cA * 8; unsigned short* lU1 = sBu + cB * 8;

  f32x4 accg[4][4] = {}, accu[4][4] = {};  // [ni][mi]

  gl16(pA0, lA0); gl16(pA1, lA1);
  gl16(pG0, lG0); gl16(pG1, lG1);
  gl16(pU0, lU0); gl16(pU1, lU1);
  pA0 += 32; pA1 += 32; pG0 += 32; pG1 += 32; pU0 += 32; pU1 += 32;

  int lrow = lane & 15, lk = (lane >> 4) * 8;
  for (int kt = 0; kt < H_ / 32; ++kt) {
    __syncthreads();  // waitcnt vmcnt(0): staged tile complete
    short8 af[4], bg[4], bu[4];
    #pragma unroll
    for (int i = 0; i < 4; ++i) {
      af[i] = *(const short8*)(sA  + (wr + i * 16 + lrow) * 32 + lk);
      bg[i] = *(const short8*)(sBg + (wc + i * 16 + lrow) * 32 + lk);
      bu[i] = *(const short8*)(sBu + (wc + i * 16 + lrow) * 32 + lk);
    }
    #pragma unroll
    for (int ni = 0; ni < 4; ++ni)
      #pragma unroll
      for (int mi = 0; mi < 4; ++mi) {
        accg[ni][mi] = __builtin_amdgcn_mfma_f32_16x16x32_bf16(bg[ni], af[mi], accg[ni][mi], 0, 0, 0);
        accu[ni][mi] = __builtin_amdgcn_mfma_f32_16x16x32_bf16(bu[ni], af[mi], accu[ni][mi], 0, 0, 0);
      }
    __syncthreads();  // all waves done reading LDS
    if (kt + 1 < H_ / 32) {
      gl16(pA0, lA0); gl16(pA1, lA1);
      gl16(pG0, lG0); gl16(pG1, lG1);
      gl16(pU0, lU0); gl16(pU1, lU1);
      pA0 += 32; pA1 += 32; pG0 += 32; pG1 += 32; pU0 += 32; pU1 += 32;
    }
  }

  // Epilogue: LoRA rank-8 delta + silu; lane holds 4 consecutive cols -> ushort4
  float* sE  = (float*)smem;
  float* sLo = sE;            // 128 x 8
  float* sBg8 = sE + 1024;
  float* sBu8 = sE + 2048;
  {
    const float* lowb = low + ((long)(e * T_) + mt * 128) * R_;
    const float* bgr  = Bgu + ((long)e * TWO_D_ + nt * 128) * R_;
    const float* bur  = Bgu + ((long)e * TWO_D_ + D_ + nt * 128) * R_;
    ((f32x4*)sLo)[tid]  = *(const f32x4*)(lowb + tid * 4);
    ((f32x4*)sBg8)[tid] = *(const f32x4*)(bgr + tid * 4);
    ((f32x4*)sBu8)[tid] = *(const f32x4*)(bur + tid * 4);
  }
  __syncthreads();
  int lq = lane >> 4;
  #pragma unroll
  for (int mi = 0; mi < 4; ++mi) {
    int tl = wr + mi * 16 + lrow;
    const float* lo8 = sLo + tl * 8;
    long rowoff = ((long)(e * T_) + mt * 128 + tl) * D_ + nt * 128;
    #pragma unroll
    for (int ni = 0; ni < 4; ++ni) {
      int cb = wc + ni * 16 + lq * 4;
      ushort4 o;
      #pragma unroll
      for (int j = 0; j < 4; ++j) {
        const float* bg8 = sBg8 + (cb + j) * 8;
        const float* bu8 = sBu8 + (cb + j) * 8;
        float dg = 0.f, du = 0.f;
        #pragma unroll
        for (int r = 0; r < 8; ++r) { dg += lo8[r] * bg8[r]; du += lo8[r] * bu8[r]; }
        float gate = accg[ni][mi][j] + SCALE_ * dg;
        float up   = accu[ni][mi][j] + SCALE_ * du;
        float hh = up * (gate / (1.f + __expf(-gate)));
        (&o.x)[j] = f2bf(hh);
      }
      *(ushort4*)(Hout + rowoff + cb) = o;
    }
  }
}

// ---------------- GEMM2 v2: out = h@Wd^T + SCALE*low2@Bd^T (fp32 out, coalesced f32x4)
__global__ __launch_bounds__(256, 2) void k_gemm2b(
    const unsigned short* __restrict__ Hin, const unsigned short* __restrict__ Wdb,
    const float* __restrict__ Bd, const float* __restrict__ low,
    float* __restrict__ Out) {
  __shared__ __align__(16) unsigned short smem[2 * 128 * 32];
  unsigned short* sA = smem;
  unsigned short* sB = smem + 128 * 32;

  const int MT = T_ / 128, NT = H_ / 128;  // 16, 16
  int b = blockIdx.x;
  int cpx = (int)gridDim.x >> 3;
  int swz = (b & 7) * cpx + (b >> 3);
  int e  = swz / (MT * NT);
  int r0 = swz % (MT * NT);
  int nt = r0 / MT, mt = r0 % MT;

  int tid = threadIdx.x, lane = tid & 63, w = tid >> 6;
  int wr = (w >> 1) * 64, wc = (w & 1) * 64;

  int cA = tid, cB = 256 + tid;
  int arA = cA >> 2, acA = (cA & 3) * 8;
  int arB = cB >> 2, acB = (cB & 3) * 8;
  const unsigned short* pA0 = Hin + ((long)(e * T_) + mt * 128 + arA) * D_ + acA;
  const unsigned short* pA1 = Hin + ((long)(e * T_) + mt * 128 + arB) * D_ + acB;
  const unsigned short* pB0 = Wdb + ((long)e * H_ + nt * 128 + arA) * (long)D_ + acA;
  const unsigned short* pB1 = Wdb + ((long)e * H_ + nt * 128 + arB) * (long)D_ + acB;
  unsigned short* lA0 = sA + cA * 8; unsigned short* lA1 = sA + cB * 8;
  unsigned short* lB0 = sB + cA * 8; unsigned short* lB1 = sB + cB * 8;

  f32x4 acc[4][4] = {};  // [ni][mi]

  gl16(pA0, lA0); gl16(pA1, lA1); gl16(pB0, lB0); gl16(pB1, lB1);
  pA0 += 32; pA1 += 32; pB0 += 32; pB1 += 32;

  int lrow = lane & 15, lk = (lane >> 4) * 8;
  for (int kt = 0; kt < D_ / 32; ++kt) {
    __syncthreads();
    short8 af[4], bf[4];
    #pragma unroll
    for (int i = 0; i < 4; ++i) {
      af[i] = *(const short8*)(sA + (wr + i * 16 + lrow) * 32 + lk);
      bf[i] = *(const short8*)(sB + (wc + i * 16 + lrow) * 32 + lk);
    }
    #pragma unroll
    for (int ni = 0; ni < 4; ++ni)
      #pragma unroll
      for (int mi = 0; mi < 4; ++mi)
        acc[ni][mi] = __builtin_amdgcn_mfma_f32_16x16x32_bf16(bf[ni], af[mi], acc[ni][mi], 0, 0, 0);
    __syncthreads();
    if (kt + 1 < D_ / 32) {
      gl16(pA0, lA0); gl16(pA1, lA1); gl16(pB0, lB0); gl16(pB1, lB1);
      pA0 += 32; pA1 += 32; pB0 += 32; pB1 += 32;
    }
  }

  float* sE  = (float*)smem;
  float* sLo = sE;
  float* sBd8 = sE + 1024;
  {
    const float* lowb = low + ((long)(e * T_) + mt * 128) * R_;
    const float* bdr  = Bd + ((long)e * H_ + nt * 128) * R_;
    ((f32x4*)sLo)[tid]  = *(const f32x4*)(lowb + tid * 4);
    ((f32x4*)sBd8)[tid] = *(const f32x4*)(bdr + tid * 4);
  }
  __syncthreads();
  int lq = lane >> 4;
  #pragma unroll
  for (int mi = 0; mi < 4; ++mi) {
    int tl = wr + mi * 16 + lrow;
    const float* lo8 = sLo + tl * 8;
    long rowoff = ((long)(e * T_) + mt * 128 + tl) * H_ + nt * 128;
    #pragma unroll
    for (int ni = 0; ni < 4; ++ni) {
      int cb = wc + ni * 16 + lq * 4;
      f32x4 o;
      #pragma unroll
      for (int j = 0; j < 4; ++j) {
        const float* bd8 = sBd8 + (cb + j) * 8;
        float d = 0.f;
        #pragma unroll
        for (int r = 0; r < 8; ++r) d += lo8[r] * bd8[r];
        o[j] = acc[ni][mi][j] + SCALE_ * d;
      }
      *(f32x4*)(Out + rowoff + cb) = o;
    }
  }
}

// ================= fallback path (round-1 kernels, fp32-weight reg-staging) =================
__global__ __launch_bounds__(256, 2) void k_gemm1(
    const float* __restrict__ X, const float* __restrict__ Wgu,
    const float* __restrict__ Bgu, const float* __restrict__ low,
    unsigned short* __restrict__ Hout) {
  __shared__ __align__(16) unsigned short smem[3 * 128 * LDSK];
  unsigned short* sA  = smem;
  unsigned short* sBg = smem + 128 * LDSK;
  unsigned short* sBu = smem + 2 * 128 * LDSK;
  const int MT = T_ / 128, NT = D_ / 128;
  int b = blockIdx.x;
  int cpx = (int)gridDim.x >> 3;
  int swz = (b & 7) * cpx + (b >> 3);
  int e  = swz / (MT * NT);
  int r0 = swz % (MT * NT);
  int nt = r0 / MT, mt = r0 % MT;
  int tid = threadIdx.x, lane = tid & 63, w = tid >> 6;
  int wr = (w >> 1) * 64, wc = (w & 1) * 64;
  int row0 = tid >> 3, c4 = (tid & 7) * 4;
  const float* Ab  = X   + ((long)(e * T_) + mt * 128 + row0) * H_ + c4;
  const float* Bgb = Wgu + ((long)e * TWO_D_ + nt * 128 + row0) * (long)H_ + c4;
  const float* Bub = Bgb + (long)D_ * H_;
  f32x4 ra[4], rg[4], ru[4];
  f32x4 accg[4][4] = {}, accu[4][4] = {};
  #pragma unroll
  for (int k = 0; k < 4; ++k) {
    ra[k] = *(const f32x4*)(Ab  + (long)k * 32 * H_);
    rg[k] = *(const f32x4*)(Bgb + (long)k * 32 * H_);
    ru[k] = *(const f32x4*)(Bub + (long)k * 32 * H_);
  }
  for (int kt = 0; kt < H_ / 32; ++kt) {
    __syncthreads();
    #pragma unroll
    for (int k = 0; k < 4; ++k) {
      int off = (row0 + k * 32) * LDSK + c4;
      ushort4 a4; a4.x=f2bf(ra[k][0]); a4.y=f2bf(ra[k][1]); a4.z=f2bf(ra[k][2]); a4.w=f2bf(ra[k][3]);
      *(ushort4*)(sA + off) = a4;
      ushort4 g4; g4.x=f2bf(rg[k][0]); g4.y=f2bf(rg[k][1]); g4.z=f2bf(rg[k][2]); g4.w=f2bf(rg[k][3]);
      *(ushort4*)(sBg + off) = g4;
      ushort4 u4; u4.x=f2bf(ru[k][0]); u4.y=f2bf(ru[k][1]); u4.z=f2bf(ru[k][2]); u4.w=f2bf(ru[k][3]);
      *(ushort4*)(sBu + off) = u4;
    }
    __syncthreads();
    if (kt + 1 < H_ / 32) {
      int ko = (kt + 1) * 32;
      #pragma unroll
      for (int k = 0; k < 4; ++k) {
        ra[k] = *(const f32x4*)(Ab  + (long)k * 32 * H_ + ko);
        rg[k] = *(const f32x4*)(Bgb + (long)k * 32 * H_ + ko);
        ru[k] = *(const f32x4*)(Bub + (long)k * 32 * H_ + ko);
      }
    }
    int lrow = lane & 15, lk = (lane >> 4) * 8;
    short8 af[4], bg[4], bu[4];
    #pragma unroll
    for (int i = 0; i < 4; ++i) {
      af[i] = *(const short8*)(sA  + (wr + i * 16 + lrow) * LDSK + lk);
      bg[i] = *(const short8*)(sBg + (wc + i * 16 + lrow) * LDSK + lk);
      bu[i] = *(const short8*)(sBu + (wc + i * 16 + lrow) * LDSK + lk);
    }
    #pragma unroll
    for (int mi = 0; mi < 4; ++mi)
      #pragma unroll
      for (int ni = 0; ni < 4; ++ni) {
        accg[mi][ni] = __builtin_amdgcn_mfma_f32_16x16x32_bf16(af[mi], bg[ni], accg[mi][ni], 0, 0, 0);
        accu[mi][ni] = __builtin_amdgcn_mfma_f32_16x16x32_bf16(af[mi], bu[ni], accu[mi][ni], 0, 0, 0);
      }
  }
  __syncthreads();
  float* sEpi = (float*)smem;
  {
    const float* lowb = low + ((long)(e * T_) + mt * 128) * R_;
    const float* bgr  = Bgu + ((long)e * TWO_D_ + nt * 128) * R_;
    const float* bur  = Bgu + ((long)e * TWO_D_ + D_ + nt * 128) * R_;
    ((f32x4*)sEpi)[tid]          = *(const f32x4*)(lowb + tid * 4);
    ((f32x4*)(sEpi + 1024))[tid] = *(const f32x4*)(bgr + tid * 4);
    ((f32x4*)(sEpi + 2048))[tid] = *(const f32x4*)(bur + tid * 4);
  }
  __syncthreads();
  int lrow = lane & 15, lq = lane >> 4;
  #pragma unroll
  for (int mi = 0; mi < 4; ++mi) {
    #pragma unroll
    for (int ni = 0; ni < 4; ++ni) {
      int colL = wc + ni * 16 + lrow;
      const float* bg8 = sEpi + 1024 + colL * 8;
      const float* bu8 = sEpi + 2048 + colL * 8;
      #pragma unroll
      for (int j = 0; j < 4; ++j) {
        int tl = wr + mi * 16 + lq * 4 + j;
        const float* lo8 = sEpi + tl * 8;
        float dg = 0.f, du = 0.f;
        #pragma unroll
        for (int r = 0; r < 8; ++r) { dg += lo8[r] * bg8[r]; du += lo8[r] * bu8[r]; }
        float gate = accg[mi][ni][j] + SCALE_ * dg;
        float up   = accu[mi][ni][j] + SCALE_ * du;
        float h = up * (gate / (1.f + __expf(-gate)));
        Hout[((long)(e * T_) + mt * 128 + tl) * D_ + nt * 128 + colL] = f2bf(h);
      }
    }
  }
}

__global__ __launch_bounds__(256, 2) void k_gemm2(
    const unsigned short* __restrict__ Hin, const float* __restrict__ Wd,
    const float* __restrict__ Bd, const float* __restrict__ low,
    float* __restrict__ Out) {
  __shared__ __align__(16) unsigned short smem[2 * 128 * LDSK];
  unsigned short* sA = smem;
  unsigned short* sB = smem + 128 * LDSK;
  const int MT = T_ / 128, NT = H_ / 128;
  int b = blockIdx.x;
  int cpx = (int)gridDim.x >> 3;
  int swz = (b & 7) * cpx + (b >> 3);
  int e  = swz / (MT * NT);
  int r0 = swz % (MT * NT);
  int nt = r0 / MT, mt = r0 % MT;
  int tid = threadIdx.x, lane = tid & 63, w = tid >> 6;
  int wr = (w >> 1) * 64, wc = (w & 1) * 64;
  int arow0 = tid >> 2, aq = (tid & 3) * 8;
  const unsigned short* Abase = Hin + ((long)(e * T_) + mt * 128 + arow0) * D_ + aq;
  int brow0 = tid >> 3, bc4 = (tid & 7) * 4;
  const float* Bbase = Wd + ((long)e * H_ + nt * 128 + brow0) * (long)D_ + bc4;
  short8 raw[2]; f32x4 rb[4];
  f32x4 acc[4][4] = {};
  #pragma unroll
  for (int k = 0; k < 2; ++k) raw[k] = *(const short8*)(Abase + (long)k * 64 * D_);
  #pragma unroll
  for (int k = 0; k < 4; ++k) rb[k] = *(const f32x4*)(Bbase + (long)k * 32 * D_);
  for (int kt = 0; kt < D_ / 32; ++kt) {
    __syncthreads();
    #pragma unroll
    for (int k = 0; k < 2; ++k)
      *(short8*)(sA + (arow0 + k * 64) * LDSK + aq) = raw[k];
    #pragma unroll
    for (int k = 0; k < 4; ++k) {
      int off = (brow0 + k * 32) * LDSK + bc4;
      ushort4 b4; b4.x=f2bf(rb[k][0]); b4.y=f2bf(rb[k][1]); b4.z=f2bf(rb[k][2]); b4.w=f2bf(rb[k][3]);
      *(ushort4*)(sB + off) = b4;
    }
    __syncthreads();
    if (kt + 1 < D_ / 32) {
      int ko = (kt + 1) * 32;
      #pragma unroll
      for (int k = 0; k < 2; ++k) raw[k] = *(const short8*)(Abase + (long)k * 64 * D_ + ko);
      #pragma unroll
      for (int k = 0; k < 4; ++k) rb[k] = *(const f32x4*)(Bbase + (long)k * 32 * D_ + ko);
    }
    int lrow = lane & 15, lk = (lane >> 4) * 8;
    short8 af[4], bf[4];
    #pragma unroll
    for (int i = 0; i < 4; ++i) {
      af[i] = *(const short8*)(sA + (wr + i * 16 + lrow) * LDSK + lk);
      bf[i] = *(const short8*)(sB + (wc + i * 16 + lrow) * LDSK + lk);
    }
    #pragma unroll
    for (int mi = 0; mi < 4; ++mi)
      #pragma unroll
      for (int ni = 0; ni < 4; ++ni)
        acc[mi][ni] = __builtin_amdgcn_mfma_f32_16x16x32_bf16(af[mi], bf[ni], acc[mi][ni], 0, 0, 0);
  }
  __syncthreads();
  float* sEpi = (float*)smem;
  {
    const float* lowb = low + ((long)(e * T_) + mt * 128) * R_;
    const float* bdr  = Bd + ((long)e * H_ + nt * 128) * R_;
    ((f32x4*)sEpi)[tid]          = *(const f32x4*)(lowb + tid * 4);
    ((f32x4*)(sEpi + 1024))[tid] = *(const f32x4*)(bdr + tid * 4);
  }
  __syncthreads();
  int lrow = lane & 15, lq = lane >> 4;
  #pragma unroll
  for (int mi = 0; mi < 4; ++mi) {
    #pragma unroll
    for (int ni = 0; ni < 4; ++ni) {
      int colL = wc + ni * 16 + lrow;
      const float* bd8 = sEpi + 1024 + colL * 8;
      #pragma unroll
      for (int j = 0; j < 4; ++j) {
        int tl = wr + mi * 16 + lq * 4 + j;
        const float* lo8 = sEpi + tl * 8;
        float d = 0.f;
        #pragma unroll
        for (int r = 0; r < 8; ++r) d += lo8[r] * bd8[r];
        Out[((long)(e * T_) + mt * 128 + tl) * H_ + nt * 128 + colL] = acc[mi][ni][j] + SCALE_ * d;
      }
    }
  }
}

extern "C" void kernel_launch(void* const* d_in, const int* in_sizes, int n_in,
                              void* d_out, int out_size, void* d_ws, size_t ws_size,
                              hipStream_t stream) {
  const float* x   = (const float*)d_in[0];
  const float* Wgu = (const float*)d_in[1];
  const float* Agu = (const float*)d_in[2];
  const float* Bgu = (const float*)d_in[3];
  const float* Wd  = (const float*)d_in[4];
  const float* Ad  = (const float*)d_in[5];
  const float* Bd  = (const float*)d_in[6];
  float* out = (float*)d_out;

  char* ws = (char*)d_ws;
  const size_t SZ_H   = (size_t)E_ * T_ * D_ * 2;        // 128 MiB bf16 h
  const size_t SZ_LOW = (size_t)E_ * T_ * R_ * 4;        // 512 KiB
  const size_t SZ_XB  = (size_t)E_ * T_ * H_ * 2;        // 64 MiB
  const size_t SZ_WGU = (size_t)E_ * TWO_D_ * H_ * 2;    // 256 MiB
  const size_t SZ_WD  = (size_t)E_ * H_ * D_ * 2;        // 128 MiB
  const size_t NEED_FULL = SZ_H + 2 * SZ_LOW + SZ_XB + SZ_WGU + SZ_WD;

  unsigned short* hbuf = (unsigned short*)ws;
  float* low1 = (float*)(ws + SZ_H);
  float* low2 = (float*)(ws + SZ_H + SZ_LOW);

  if (ws_size >= NEED_FULL) {
    unsigned short* xb   = (unsigned short*)(ws + SZ_H + 2 * SZ_LOW);
    unsigned short* wgub = (unsigned short*)(ws + SZ_H + 2 * SZ_LOW + SZ_XB);
    unsigned short* wdb  = (unsigned short*)(ws + SZ_H + 2 * SZ_LOW + SZ_XB + SZ_WGU);

    hipLaunchKernelGGL(k_f2bf, dim3(2048), dim3(256), 0, stream, x,   xb,   (long)E_ * T_ * H_);
    hipLaunchKernelGGL(k_f2bf, dim3(2048), dim3(256), 0, stream, Wgu, wgub, (long)E_ * TWO_D_ * H_);
    hipLaunchKernelGGL(k_f2bf, dim3(2048), dim3(256), 0, stream, Wd,  wdb,  (long)E_ * H_ * D_);
    hipLaunchKernelGGL((k_low<H_, false>), dim3(E_ * T_ / 4), dim3(256), 0, stream, (const void*)x, Agu, low1);
    hipLaunchKernelGGL(k_gemm1b, dim3(E_ * (T_ / 128) * (D_ / 128)), dim3(256), 0, stream, xb, wgub, Bgu, low1, hbuf);
    hipLaunchKernelGGL((k_low<D_, true>), dim3(E_ * T_ / 4), dim3(256), 0, stream, (const void*)hbuf, Ad, low2);
    hipLaunchKernelGGL(k_gemm2b, dim3(E_ * (T_ / 128) * (H_ / 128)), dim3(256), 0, stream, hbuf, wdb, Bd, low2, out);
  } else {
    hipLaunchKernelGGL((k_low<H_, false>), dim3(E_ * T_ / 4), dim3(256), 0, stream, (const void*)x, Agu, low1);
    hipLaunchKernelGGL(k_gemm1, dim3(E_ * (T_ / 128) * (D_ / 128)), dim3(256), 0, stream, x, Wgu, Bgu, low1, hbuf);
    hipLaunchKernelGGL((k_low<D_, true>), dim3(E_ * T_ / 4), dim3(256), 0, stream, (const void*)hbuf, Ad, low2);
    hipLaunchKernelGGL(k_gemm2, dim3(E_ * (T_ / 128) * (H_ / 128)), dim3(256), 0, stream, hbuf, Wd, Bd, low2, out);
  }
}

// Round 3
// 1354.232 us; speedup vs baseline: 2.2931x; 2.2931x over previous
//
#include <hip/hip_runtime.h>
#include <hip/hip_bf16.h>

#define E_ 8
#define H_ 2048
#define D_ 4096
#define R_ 8
#define T_ 2048
#define TWO_D_ 8192
#define SCALE_ 2.0f

typedef __attribute__((ext_vector_type(8))) short short8;
typedef __attribute__((ext_vector_type(4))) float f32x4;

__device__ __forceinline__ unsigned short f2bf(float f) {
  union { float f; unsigned u; } c; c.f = f;
  unsigned u = c.u + 0x7fffu + ((c.u >> 16) & 1u);  // RNE
  return (unsigned short)(u >> 16);
}
__device__ __forceinline__ float bf2f(unsigned short s) {
  union { unsigned u; float f; } c; c.u = ((unsigned)s) << 16;
  return c.f;
}

// async 16B global -> LDS (linear dest: wave-uniform base + lane*16)
__device__ __forceinline__ void gl16(const void* g, void* l) {
  __builtin_amdgcn_global_load_lds(
      (const __attribute__((address_space(1))) void*)g,
      (__attribute__((address_space(3))) void*)l, 16, 0, 0);
}

// ---------------- rank-8 projection: low[tok][r] = sum_i X[tok][i]*A[e][r][i]
template <int K, bool XBF16>
__global__ __launch_bounds__(256) void k_low(const void* __restrict__ Xv,
                                             const float* __restrict__ A,
                                             float* __restrict__ low) {
  int wave = (blockIdx.x * 256 + threadIdx.x) >> 6;
  int lane = threadIdx.x & 63;
  int e = wave >> 11;  // / T_
  const float* Ae = A + (long)e * R_ * K;
  float acc[R_] = {0.f,0.f,0.f,0.f,0.f,0.f,0.f,0.f};
  for (int it = 0; it < K / 256; ++it) {
    int i = it * 256 + lane * 4;
    float xv[4];
    if constexpr (!XBF16) {
      const float* x = (const float*)Xv + (long)wave * K;
      f32x4 v = *(const f32x4*)(x + i);
      xv[0]=v[0]; xv[1]=v[1]; xv[2]=v[2]; xv[3]=v[3];
    } else {
      const unsigned short* x = (const unsigned short*)Xv + (long)wave * K;
      ushort4 u = *(const ushort4*)(x + i);
      xv[0]=bf2f(u.x); xv[1]=bf2f(u.y); xv[2]=bf2f(u.z); xv[3]=bf2f(u.w);
    }
    #pragma unroll
    for (int r = 0; r < R_; ++r) {
      f32x4 a = *(const f32x4*)(Ae + r * K + i);
      acc[r] += xv[0]*a[0] + xv[1]*a[1] + xv[2]*a[2] + xv[3]*a[3];
    }
  }
  #pragma unroll
  for (int r = 0; r < R_; ++r) {
    float v = acc[r];
    #pragma unroll
    for (int off = 32; off > 0; off >>= 1) v += __shfl_xor(v, off);
    acc[r] = v;
  }
  if (lane == 0) {
    #pragma unroll
    for (int r = 0; r < R_; ++r) low[(long)wave * R_ + r] = acc[r];
  }
}

// ---------------- fp32 -> bf16 bulk conversion
__global__ __launch_bounds__(256) void k_f2bf(const float* __restrict__ src,
                                              unsigned short* __restrict__ dst,
                                              long n) {
  long i = ((long)blockIdx.x * 256 + threadIdx.x) * 8;
  long stride = (long)gridDim.x * 256 * 8;
  for (; i < n; i += stride) {
    f32x4 a = *(const f32x4*)(src + i);
    f32x4 b = *(const f32x4*)(src + i + 4);
    ushort4 lo, hi;
    lo.x=f2bf(a[0]); lo.y=f2bf(a[1]); lo.z=f2bf(a[2]); lo.w=f2bf(a[3]);
    hi.x=f2bf(b[0]); hi.y=f2bf(b[1]); hi.z=f2bf(b[2]); hi.w=f2bf(b[3]);
    *(ushort4*)(dst + i) = lo;
    *(ushort4*)(dst + i + 4) = hi;
  }
}

// ---------------- GEMM1: h = up*silu(gate); gate_up = x@Wgu^T + SCALE*low1@Bgu^T
// m97 2-phase: double-buffered LDS {A,G,U}x8KB, stage t+1 before compute t,
// single vmcnt(0)+barrier per K-step.
__global__ __launch_bounds__(256, 2) void k_gemm1b(
    const unsigned short* __restrict__ Xb, const unsigned short* __restrict__ Wb,
    const float* __restrict__ Bgu, const float* __restrict__ low,
    unsigned short* __restrict__ Hout) {
  __shared__ __align__(16) char smemc[49152];  // 2 x {A 8K, G 8K, U 8K}

  const int MT = T_ / 128, NT = D_ / 128;  // 16, 32
  int b = blockIdx.x;
  int cpx = (int)gridDim.x >> 3;
  int swz = (b & 7) * cpx + (b >> 3);     // bijective: grid % 8 == 0
  int e  = swz / (MT * NT);
  int r0 = swz % (MT * NT);
  int nt = r0 / MT, mt = r0 % MT;

  int tid = threadIdx.x, lane = tid & 63, w = tid >> 6;
  int wr = (w >> 1) * 64, wc = (w & 1) * 64;

  // staging: chunk c (16B) -> LDS byte c*16 within region; row=c>>2, col=(c&3)*8
  int cA = tid, cB = tid + 256;
  int arA = cA >> 2, acA = (cA & 3) * 8;
  int arB = cB >> 2, acB = (cB & 3) * 8;
  const unsigned short* pA0 = Xb + ((long)(e * T_) + mt * 128 + arA) * H_ + acA;
  const unsigned short* pA1 = Xb + ((long)(e * T_) + mt * 128 + arB) * H_ + acB;
  const unsigned short* pG0 = Wb + ((long)e * TWO_D_ + nt * 128 + arA) * (long)H_ + acA;
  const unsigned short* pG1 = Wb + ((long)e * TWO_D_ + nt * 128 + arB) * (long)H_ + acB;
  const unsigned short* pU0 = pG0 + (long)D_ * H_;
  const unsigned short* pU1 = pG1 + (long)D_ * H_;
  const int oA0 = cA * 16, oA1 = cB * 16;
  const int oG0 = 8192 + cA * 16, oG1 = 8192 + cB * 16;
  const int oU0 = 16384 + cA * 16, oU1 = 16384 + cB * 16;

  f32x4 accg[4][4] = {}, accu[4][4] = {};  // [ni][mi]

  auto STAGE = [&](unsigned off) {
    char* s = smemc + off;
    gl16(pA0, s + oA0); gl16(pA1, s + oA1);
    gl16(pG0, s + oG0); gl16(pG1, s + oG1);
    gl16(pU0, s + oU0); gl16(pU1, s + oU1);
    pA0 += 32; pA1 += 32; pG0 += 32; pG1 += 32; pU0 += 32; pU1 += 32;
  };

  STAGE(0);
  __syncthreads();

  int lrow = lane & 15;
  int lkB = (lane >> 4) * 16;  // byte offset of k-chunk within 64B row
  unsigned roff = 0;
  for (int kt = 0; kt < H_ / 32; ++kt) {
    if (kt + 1 < H_ / 32) STAGE(roff ^ 24576u);  // loads fly during MFMA below
    short8 af[4], bg[4], bu[4];
    #pragma unroll
    for (int i = 0; i < 4; ++i) {
      const char* base = smemc + roff + (unsigned)((wr + i * 16 + lrow) * 64 + lkB);
      af[i] = *(const short8*)(base);
      bg[i] = *(const short8*)(smemc + roff + 8192u + (unsigned)((wc + i * 16 + lrow) * 64 + lkB));
      bu[i] = *(const short8*)(smemc + roff + 16384u + (unsigned)((wc + i * 16 + lrow) * 64 + lkB));
    }
    #pragma unroll
    for (int ni = 0; ni < 4; ++ni)
      #pragma unroll
      for (int mi = 0; mi < 4; ++mi) {
        accg[ni][mi] = __builtin_amdgcn_mfma_f32_16x16x32_bf16(bg[ni], af[mi], accg[ni][mi], 0, 0, 0);
        accu[ni][mi] = __builtin_amdgcn_mfma_f32_16x16x32_bf16(bu[ni], af[mi], accu[ni][mi], 0, 0, 0);
      }
    __syncthreads();  // drains this step's stage (vmcnt 0) + guards buffer swap
    roff ^= 24576u;
  }

  // Epilogue: rank-8 delta + silu -> bf16, transposed through LDS for coalesced stores
  float* sLo  = (float*)(smemc + 35840);  // 128 x 8
  float* sBg8 = (float*)(smemc + 39936);
  float* sBu8 = (float*)(smemc + 44032);
  {
    const float* lowb = low + ((long)(e * T_) + mt * 128) * R_;
    const float* bgr  = Bgu + ((long)e * TWO_D_ + nt * 128) * R_;
    const float* bur  = Bgu + ((long)e * TWO_D_ + D_ + nt * 128) * R_;
    ((f32x4*)sLo)[tid]  = *(const f32x4*)(lowb + tid * 4);
    ((f32x4*)sBg8)[tid] = *(const f32x4*)(bgr + tid * 4);
    ((f32x4*)sBu8)[tid] = *(const f32x4*)(bur + tid * 4);
  }
  __syncthreads();
  unsigned short* sT = (unsigned short*)smemc;  // [128][136] padded bf16 tile
  int lq = lane >> 4;
  #pragma unroll
  for (int mi = 0; mi < 4; ++mi) {
    int tl = wr + mi * 16 + lrow;
    const float* lo8 = sLo + tl * 8;
    #pragma unroll
    for (int ni = 0; ni < 4; ++ni) {
      int cb = wc + ni * 16 + lq * 4;
      ushort4 o;
      #pragma unroll
      for (int j = 0; j < 4; ++j) {
        const float* bg8 = sBg8 + (cb + j) * 8;
        const float* bu8 = sBu8 + (cb + j) * 8;
        float dg = 0.f, du = 0.f;
        #pragma unroll
        for (int r = 0; r < 8; ++r) { dg += lo8[r] * bg8[r]; du += lo8[r] * bu8[r]; }
        float gate = accg[ni][mi][j] + SCALE_ * dg;
        float up   = accu[ni][mi][j] + SCALE_ * du;
        float hh = up * (gate / (1.f + __expf(-gate)));
        (&o.x)[j] = f2bf(hh);
      }
      *(ushort4*)(sT + tl * 136 + cb) = o;
    }
  }
  __syncthreads();
  {
    long base = ((long)(e * T_) + mt * 128) * D_ + nt * 128;
    int rr = tid >> 4, cc = (tid & 15) * 8;
    #pragma unroll
    for (int p = 0; p < 8; ++p) {
      int r = p * 16 + rr;
      short8 v = *(const short8*)(sT + r * 136 + cc);
      *(short8*)(Hout + base + (long)r * D_ + cc) = v;
    }
  }
}

// ---------------- GEMM2: out = h@Wd^T + SCALE*low2@Bd^T (fp32 out)
__global__ __launch_bounds__(256, 2) void k_gemm2b(
    const unsigned short* __restrict__ Hin, const unsigned short* __restrict__ Wdb,
    const float* __restrict__ Bd, const float* __restrict__ low,
    float* __restrict__ Out) {
  __shared__ __align__(16) char smemc[32768];  // 2 x {A 8K, B 8K}

  const int MT = T_ / 128, NT = H_ / 128;  // 16, 16
  int b = blockIdx.x;
  int cpx = (int)gridDim.x >> 3;
  int swz = (b & 7) * cpx + (b >> 3);
  int e  = swz / (MT * NT);
  int r0 = swz % (MT * NT);
  int nt = r0 / MT, mt = r0 % MT;

  int tid = threadIdx.x, lane = tid & 63, w = tid >> 6;
  int wr = (w >> 1) * 64, wc = (w & 1) * 64;

  int cA = tid, cB = tid + 256;
  int arA = cA >> 2, acA = (cA & 3) * 8;
  int arB = cB >> 2, acB = (cB & 3) * 8;
  const unsigned short* pA0 = Hin + ((long)(e * T_) + mt * 128 + arA) * D_ + acA;
  const unsigned short* pA1 = Hin + ((long)(e * T_) + mt * 128 + arB) * D_ + acB;
  const unsigned short* pB0 = Wdb + ((long)e * H_ + nt * 128 + arA) * (long)D_ + acA;
  const unsigned short* pB1 = Wdb + ((long)e * H_ + nt * 128 + arB) * (long)D_ + acB;
  const int oA0 = cA * 16, oA1 = cB * 16;
  const int oB0 = 8192 + cA * 16, oB1 = 8192 + cB * 16;

  f32x4 acc[4][4] = {};  // [ni][mi]

  auto STAGE = [&](unsigned off) {
    char* s = smemc + off;
    gl16(pA0, s + oA0); gl16(pA1, s + oA1);
    gl16(pB0, s + oB0); gl16(pB1, s + oB1);
    pA0 += 32; pA1 += 32; pB0 += 32; pB1 += 32;
  };

  STAGE(0);
  __syncthreads();

  int lrow = lane & 15;
  int lkB = (lane >> 4) * 16;
  unsigned roff = 0;
  for (int kt = 0; kt < D_ / 32; ++kt) {
    if (kt + 1 < D_ / 32) STAGE(roff ^ 16384u);
    short8 af[4], bf[4];
    #pragma unroll
    for (int i = 0; i < 4; ++i) {
      af[i] = *(const short8*)(smemc + roff + (unsigned)((wr + i * 16 + lrow) * 64 + lkB));
      bf[i] = *(const short8*)(smemc + roff + 8192u + (unsigned)((wc + i * 16 + lrow) * 64 + lkB));
    }
    #pragma unroll
    for (int ni = 0; ni < 4; ++ni)
      #pragma unroll
      for (int mi = 0; mi < 4; ++mi)
        acc[ni][mi] = __builtin_amdgcn_mfma_f32_16x16x32_bf16(bf[ni], af[mi], acc[ni][mi], 0, 0, 0);
    __syncthreads();
    roff ^= 16384u;
  }

  float* sLo  = (float*)smemc;          // 4KB
  float* sBd8 = (float*)(smemc + 4096); // 4KB
  {
    const float* lowb = low + ((long)(e * T_) + mt * 128) * R_;
    const float* bdr  = Bd + ((long)e * H_ + nt * 128) * R_;
    ((f32x4*)sLo)[tid]  = *(const f32x4*)(lowb + tid * 4);
    ((f32x4*)sBd8)[tid] = *(const f32x4*)(bdr + tid * 4);
  }
  __syncthreads();
  int lq = lane >> 4;
  #pragma unroll
  for (int mi = 0; mi < 4; ++mi) {
    int tl = wr + mi * 16 + lrow;
    const float* lo8 = sLo + tl * 8;
    long rowoff = ((long)(e * T_) + mt * 128 + tl) * H_ + nt * 128;
    #pragma unroll
    for (int ni = 0; ni < 4; ++ni) {
      int cb = wc + ni * 16 + lq * 4;
      f32x4 o;
      #pragma unroll
      for (int j = 0; j < 4; ++j) {
        const float* bd8 = sBd8 + (cb + j) * 8;
        float d = 0.f;
        #pragma unroll
        for (int r = 0; r < 8; ++r) d += lo8[r] * bd8[r];
        o[j] = acc[ni][mi][j] + SCALE_ * d;
      }
      *(f32x4*)(Out + rowoff + cb) = o;  // 4 lanes x 16B contiguous per 64B sector
    }
  }
}

extern "C" void kernel_launch(void* const* d_in, const int* in_sizes, int n_in,
                              void* d_out, int out_size, void* d_ws, size_t ws_size,
                              hipStream_t stream) {
  const float* x   = (const float*)d_in[0];
  const float* Wgu = (const float*)d_in[1];
  const float* Agu = (const float*)d_in[2];
  const float* Bgu = (const float*)d_in[3];
  const float* Wd  = (const float*)d_in[4];
  const float* Ad  = (const float*)d_in[5];
  const float* Bd  = (const float*)d_in[6];
  float* out = (float*)d_out;

  char* ws = (char*)d_ws;
  const size_t SZ_H   = (size_t)E_ * T_ * D_ * 2;        // 128 MiB bf16 h
  const size_t SZ_LOW = (size_t)E_ * T_ * R_ * 4;        // 512 KiB
  const size_t SZ_XB  = (size_t)E_ * T_ * H_ * 2;        // 64 MiB
  const size_t SZ_WGU = (size_t)E_ * TWO_D_ * H_ * 2;    // 256 MiB

  unsigned short* hbuf = (unsigned short*)ws;
  float* low1 = (float*)(ws + SZ_H);
  float* low2 = (float*)(ws + SZ_H + SZ_LOW);
  unsigned short* xb   = (unsigned short*)(ws + SZ_H + 2 * SZ_LOW);
  unsigned short* wgub = (unsigned short*)(ws + SZ_H + 2 * SZ_LOW + SZ_XB);
  unsigned short* wdb  = (unsigned short*)(ws + SZ_H + 2 * SZ_LOW + SZ_XB + SZ_WGU);

  hipLaunchKernelGGL(k_f2bf, dim3(2048), dim3(256), 0, stream, x,   xb,   (long)E_ * T_ * H_);
  hipLaunchKernelGGL(k_f2bf, dim3(2048), dim3(256), 0, stream, Wgu, wgub, (long)E_ * TWO_D_ * H_);
  hipLaunchKernelGGL(k_f2bf, dim3(2048), dim3(256), 0, stream, Wd,  wdb,  (long)E_ * H_ * D_);
  hipLaunchKernelGGL((k_low<H_, false>), dim3(E_ * T_ / 4), dim3(256), 0, stream, (const void*)x, Agu, low1);
  hipLaunchKernelGGL(k_gemm1b, dim3(E_ * (T_ / 128) * (D_ / 128)), dim3(256), 0, stream, xb, wgub, Bgu, low1, hbuf);
  hipLaunchKernelGGL((k_low<D_, true>), dim3(E_ * T_ / 4), dim3(256), 0, stream, (const void*)hbuf, Ad, low2);
  hipLaunchKernelGGL(k_gemm2b, dim3(E_ * (T_ / 128) * (H_ / 128)), dim3(256), 0, stream, hbuf, wdb, Bd, low2, out);
}

// Round 4
// 1168.152 us; speedup vs baseline: 2.6584x; 1.1593x over previous
//
#include <hip/hip_runtime.h>
#include <hip/hip_bf16.h>

#define E_ 8
#define H_ 2048
#define D_ 4096
#define R_ 8
#define T_ 2048
#define TWO_D_ 8192
#define SCALE_ 2.0f

typedef __attribute__((ext_vector_type(8))) short short8;
typedef __attribute__((ext_vector_type(4))) float f32x4;

__device__ __forceinline__ unsigned short f2bf(float f) {
  union { float f; unsigned u; } c; c.f = f;
  unsigned u = c.u + 0x7fffu + ((c.u >> 16) & 1u);  // RNE
  return (unsigned short)(u >> 16);
}
__device__ __forceinline__ float bf2f(unsigned short s) {
  union { unsigned u; float f; } c; c.u = ((unsigned)s) << 16;
  return c.f;
}

// async 16B global -> LDS (linear dest: wave-uniform base + lane*16)
__device__ __forceinline__ void gl16(const void* g, void* l) {
  __builtin_amdgcn_global_load_lds(
      (const __attribute__((address_space(1))) void*)g,
      (__attribute__((address_space(3))) void*)l, 16, 0, 0);
}

// LDS byte offset inside a 32KB operand region laid out [qtr][half][32 rows][64 cols bf16]
__device__ __forceinline__ int lds_off(int rr, int ks, int lq) {
  return (((rr >> 5) & 3) << 13) | (((rr >> 7) & 1) << 12) | ((rr & 31) << 7) | (ks << 6) | (lq << 4);
}

// ---------------- rank-8 projection (+ optional bf16 copy of input)
template <int K, bool XBF16, bool WRITEXB>
__global__ __launch_bounds__(256) void k_low(const void* __restrict__ Xv,
                                             const float* __restrict__ A,
                                             float* __restrict__ low,
                                             unsigned short* __restrict__ xbout) {
  int wave = (blockIdx.x * 256 + threadIdx.x) >> 6;
  int lane = threadIdx.x & 63;
  int e = wave >> 11;  // / T_
  const float* Ae = A + (long)e * R_ * K;
  float acc[R_] = {0.f,0.f,0.f,0.f,0.f,0.f,0.f,0.f};
  for (int it = 0; it < K / 256; ++it) {
    int i = it * 256 + lane * 4;
    float xv[4];
    if constexpr (!XBF16) {
      const float* x = (const float*)Xv + (long)wave * K;
      f32x4 v = *(const f32x4*)(x + i);
      xv[0]=v[0]; xv[1]=v[1]; xv[2]=v[2]; xv[3]=v[3];
      if constexpr (WRITEXB) {
        ushort4 u; u.x=f2bf(xv[0]); u.y=f2bf(xv[1]); u.z=f2bf(xv[2]); u.w=f2bf(xv[3]);
        *(ushort4*)(xbout + (long)wave * K + i) = u;
      }
    } else {
      const unsigned short* x = (const unsigned short*)Xv + (long)wave * K;
      ushort4 u = *(const ushort4*)(x + i);
      xv[0]=bf2f(u.x); xv[1]=bf2f(u.y); xv[2]=bf2f(u.z); xv[3]=bf2f(u.w);
    }
    #pragma unroll
    for (int r = 0; r < R_; ++r) {
      f32x4 a = *(const f32x4*)(Ae + r * K + i);
      acc[r] += xv[0]*a[0] + xv[1]*a[1] + xv[2]*a[2] + xv[3]*a[3];
    }
  }
  #pragma unroll
  for (int r = 0; r < R_; ++r) {
    float v = acc[r];
    #pragma unroll
    for (int off = 32; off > 0; off >>= 1) v += __shfl_xor(v, off);
    acc[r] = v;
  }
  if (lane == 0) {
    #pragma unroll
    for (int r = 0; r < R_; ++r) low[(long)wave * R_ + r] = acc[r];
  }
}

// ---------------- fp32 -> bf16 bulk conversion
__global__ __launch_bounds__(256) void k_f2bf(const float* __restrict__ src,
                                              unsigned short* __restrict__ dst,
                                              long n) {
  long i = ((long)blockIdx.x * 256 + threadIdx.x) * 8;
  long stride = (long)gridDim.x * 256 * 8;
  for (; i < n; i += stride) {
    f32x4 a = *(const f32x4*)(src + i);
    f32x4 b = *(const f32x4*)(src + i + 4);
    ushort4 lo, hi;
    lo.x=f2bf(a[0]); lo.y=f2bf(a[1]); lo.z=f2bf(a[2]); lo.w=f2bf(a[3]);
    hi.x=f2bf(b[0]); hi.y=f2bf(b[1]); hi.z=f2bf(b[2]); hi.w=f2bf(b[3]);
    *(ushort4*)(dst + i) = lo;
    *(ushort4*)(dst + i + 4) = hi;
  }
}

// ======================= GEMM1: 256x128(gate)+128(up), BK=64, 8-phase =======================
// h = up*silu(gate); gate_up = x@Wgu^T + SCALE*low1@Bgu^T   (LoRA folded as rank-8 MFMA step)
__global__ __launch_bounds__(512, 2) void k_gemm1_8p(
    const unsigned short* __restrict__ Xb, const unsigned short* __restrict__ Wb,
    const float* __restrict__ Bgu, const float* __restrict__ low,
    unsigned short* __restrict__ Hout) {
  __shared__ __align__(16) char lds[131072];  // A: d*32768, B: 65536 + d*32768

  const int MT = T_ / 256, NT = D_ / 128;  // 8, 32
  int b = blockIdx.x;
  int cpx = (int)gridDim.x >> 3;
  int swz = (b & 7) * cpx + (b >> 3);
  int e  = swz / (MT * NT);
  int r0 = swz % (MT * NT);
  int nt = r0 / MT, mt = r0 % MT;

  int tid = threadIdx.x, lane = tid & 63;
  int wid = tid >> 6, wm = wid >> 2, wn = wid & 3;
  int lrow = lane & 15, lq = lane >> 4;
  int X4 = (lrow & 3) << 4;
  const int NKT = H_ / 64;  // 32

  // ---- staging source pointers (inverse-swizzled global source, linear LDS dest)
  unsigned ro = (unsigned)tid * 16;
  unsigned so = ro ^ (((ro >> 7) & 3u) << 4);
  int sh = (so >> 12) & 1, sr = (so >> 7) & 31, sc = (so & 127) >> 1;
  const unsigned short* pA[4]; const unsigned short* pB[4];
  #pragma unroll
  for (int q = 0; q < 4; ++q) {
    long arow = (long)e * T_ + mt * 256 + sh * 128 + q * 32 + sr;
    pA[q] = Xb + arow * H_ + sc;
    long wrow = sh ? ((long)e * TWO_D_ + D_ + nt * 128 + q * 32 + sr)
                   : ((long)e * TWO_D_ +      nt * 128 + q * 32 + sr);
    pB[q] = Wb + wrow * (long)H_ + sc;
  }
  auto SA = [&](int d, int q) { gl16(pA[q], lds + d * 32768 + q * 8192 + ro); pA[q] += 64; };
  auto SB = [&](int d, int q) { gl16(pB[q], lds + 65536 + d * 32768 + q * 8192 + ro); pB[q] += 64; };

  f32x4 accg[2][8] = {}, accu[2][8] = {};  // [nj][mi]
  short8 BG[2][2], BU[2][2], af[2][2];

  // ---- prologue: tile0 all 8 units, tile1 first 6 units; wait tile0 complete
  SA(0,0); SB(0,0); SA(0,1); SB(0,1); SA(0,2); SB(0,2); SA(0,3); SB(0,3);
  SA(1,0); SB(1,0); SA(1,1); SB(1,1); SA(1,2); SB(1,2);
  asm volatile("s_waitcnt vmcnt(6)" ::: "memory");
  __builtin_amdgcn_s_barrier();

  int rbA = wm * 128 + lrow;
  for (int t = 0; t < NKT; ++t) {
    int d = t & 1;
    const char* Ab = lds + d * 32768;
    const char* Bb = lds + 65536 + d * 32768;

#define G1_MFMA(q)                                                                   \
    __builtin_amdgcn_s_setprio(1);                                                   \
    _Pragma("unroll") for (int m2 = 0; m2 < 2; ++m2)                                 \
      _Pragma("unroll") for (int ks = 0; ks < 2; ++ks)                               \
        _Pragma("unroll") for (int nj = 0; nj < 2; ++nj) {                           \
          accg[nj][(q)*2+m2] = __builtin_amdgcn_mfma_f32_16x16x32_bf16(              \
              BG[nj][ks], af[m2][ks], accg[nj][(q)*2+m2], 0, 0, 0);                  \
          accu[nj][(q)*2+m2] = __builtin_amdgcn_mfma_f32_16x16x32_bf16(              \
              BU[nj][ks], af[m2][ks], accu[nj][(q)*2+m2], 0, 0, 0);                  \
        }                                                                            \
    __builtin_amdgcn_s_setprio(0);

#define G1_LDA(q)                                                                    \
    _Pragma("unroll") for (int m2 = 0; m2 < 2; ++m2)                                 \
      _Pragma("unroll") for (int ks = 0; ks < 2; ++ks)                               \
        af[m2][ks] = *(const short8*)(Ab + (lds_off(rbA + ((q)*2+m2)*16, ks, lq) ^ X4));

#define G1_SYNC()                                                                    \
    __builtin_amdgcn_s_barrier();                                                    \
    asm volatile("s_waitcnt lgkmcnt(0)" ::: "memory");                               \
    __builtin_amdgcn_sched_barrier(0);

    // phase 0: B-frags + A-quad0; stage tile t+1 last units
    #pragma unroll
    for (int nj = 0; nj < 2; ++nj)
      #pragma unroll
      for (int ks = 0; ks < 2; ++ks) {
        int rg = wn * 32 + nj * 16 + lrow;
        BG[nj][ks] = *(const short8*)(Bb + (lds_off(rg, ks, lq) ^ X4));
        BU[nj][ks] = *(const short8*)(Bb + (lds_off(rg + 128, ks, lq) ^ X4));
      }
    G1_LDA(0);
    if (t + 1 < NKT) { SA(d ^ 1, 3); SB(d ^ 1, 3); }
    G1_SYNC();
    G1_MFMA(0);
    __builtin_amdgcn_s_barrier();
    // phase 1
    G1_LDA(1);
    if (t + 2 < NKT) { SA(d, 0); SB(d, 0); }
    G1_SYNC();
    G1_MFMA(1);
    __builtin_amdgcn_s_barrier();
    // phase 2
    G1_LDA(2);
    if (t + 2 < NKT) { SA(d, 1); SB(d, 1); }
    G1_SYNC();
    G1_MFMA(2);
    __builtin_amdgcn_s_barrier();
    // phase 3 (counted vmcnt: 6 loads of tile t+2 may stay in flight)
    G1_LDA(3);
    if (t + 2 < NKT) {
      SA(d, 2); SB(d, 2);
      asm volatile("s_waitcnt vmcnt(6)" ::: "memory");
    } else {
      asm volatile("s_waitcnt vmcnt(0)" ::: "memory");
    }
    G1_SYNC();
    G1_MFMA(3);
    __builtin_amdgcn_s_barrier();
  }

  // ---- epilogue: fold LoRA via one rank-8 (K=32 zero-padded) MFMA step
  __syncthreads();
  unsigned short* sLo2 = (unsigned short*)lds;            // [256][32] bf16: SCALE*low1
  unsigned short* sB2  = (unsigned short*)(lds + 16384);  // [256][32] bf16: Bgu rows (gate|up)
  {
    short8 z = {};
    if (tid < 256) {
      const float* lp = low + ((long)e * T_ + mt * 256 + tid) * R_;
      short8 v;
      #pragma unroll
      for (int r = 0; r < 8; ++r) ((unsigned short*)&v)[r] = f2bf(SCALE_ * lp[r]);
      *(short8*)(sLo2 + tid * 32) = v;
      *(short8*)(sLo2 + tid * 32 + 8) = z;
      *(short8*)(sLo2 + tid * 32 + 16) = z;
      *(short8*)(sLo2 + tid * 32 + 24) = z;
    } else {
      int r = tid - 256;
      long wrow = (r < 128) ? ((long)e * TWO_D_ + nt * 128 + r)
                            : ((long)e * TWO_D_ + D_ + nt * 128 + (r - 128));
      const float* bp = Bgu + wrow * R_;
      short8 v;
      #pragma unroll
      for (int k = 0; k < 8; ++k) ((unsigned short*)&v)[k] = f2bf(bp[k]);
      *(short8*)(sB2 + r * 32) = v;
      *(short8*)(sB2 + r * 32 + 8) = z;
      *(short8*)(sB2 + r * 32 + 16) = z;
      *(short8*)(sB2 + r * 32 + 24) = z;
    }
  }
  __syncthreads();
  {
    #pragma unroll
    for (int mi = 0; mi < 8; ++mi) {
      short8 alo = *(const short8*)(sLo2 + (rbA + mi * 16) * 32 + lq * 8);
      #pragma unroll
      for (int nj = 0; nj < 2; ++nj) {
        int rg = wn * 32 + nj * 16 + lrow;
        short8 bg2 = *(const short8*)(sB2 + rg * 32 + lq * 8);
        short8 bu2 = *(const short8*)(sB2 + (rg + 128) * 32 + lq * 8);
        accg[nj][mi] = __builtin_amdgcn_mfma_f32_16x16x32_bf16(bg2, alo, accg[nj][mi], 0, 0, 0);
        accu[nj][mi] = __builtin_amdgcn_mfma_f32_16x16x32_bf16(bu2, alo, accu[nj][mi], 0, 0, 0);
      }
    }
  }
  // silu + pack -> sT [256][136], then coalesced store
  unsigned short* sT = (unsigned short*)(lds + 32768);
  #pragma unroll
  for (int mi = 0; mi < 8; ++mi) {
    int tl = rbA + mi * 16;
    #pragma unroll
    for (int nj = 0; nj < 2; ++nj) {
      int cb = wn * 32 + nj * 16 + lq * 4;
      ushort4 o;
      #pragma unroll
      for (int j = 0; j < 4; ++j) {
        float gate = accg[nj][mi][j];
        float up   = accu[nj][mi][j];
        float hh = up * (gate / (1.f + __expf(-gate)));
        (&o.x)[j] = f2bf(hh);
      }
      *(ushort4*)(sT + tl * 136 + cb) = o;
    }
  }
  __syncthreads();
  {
    long base = ((long)e * T_ + mt * 256) * D_ + nt * 128;
    int rr2 = tid >> 4, cc2 = (tid & 15) * 8;
    #pragma unroll
    for (int p = 0; p < 8; ++p) {
      int r = p * 32 + rr2;
      short8 v = *(const short8*)(sT + r * 136 + cc2);
      *(short8*)(Hout + base + (long)r * D_ + cc2) = v;
    }
  }
}

// ======================= GEMM2: 256x256, BK=64, 8-phase =======================
// out = h@Wd^T + SCALE*low2@Bd^T (fp32 out; LoRA folded as rank-8 MFMA step)
__global__ __launch_bounds__(512, 2) void k_gemm2_8p(
    const unsigned short* __restrict__ Hin, const unsigned short* __restrict__ Wdb,
    const float* __restrict__ Bd, const float* __restrict__ low,
    float* __restrict__ Out) {
  __shared__ __align__(16) char lds[131072];

  const int MT = T_ / 256, NT = H_ / 256;  // 8, 8
  int b = blockIdx.x;
  int cpx = (int)gridDim.x >> 3;
  int swz = (b & 7) * cpx + (b >> 3);
  int e  = swz / (MT * NT);
  int r0 = swz % (MT * NT);
  int nt = r0 / MT, mt = r0 % MT;

  int tid = threadIdx.x, lane = tid & 63;
  int wid = tid >> 6, wm = wid >> 2, wn = wid & 3;
  int lrow = lane & 15, lq = lane >> 4;
  int X4 = (lrow & 3) << 4;
  const int NKT = D_ / 64;  // 64

  unsigned ro = (unsigned)tid * 16;
  unsigned so = ro ^ (((ro >> 7) & 3u) << 4);
  int sh = (so >> 12) & 1, sr = (so >> 7) & 31, sc = (so & 127) >> 1;
  const unsigned short* pA[4]; const unsigned short* pB[4];
  #pragma unroll
  for (int q = 0; q < 4; ++q) {
    long arow = (long)e * T_ + mt * 256 + sh * 128 + q * 32 + sr;
    pA[q] = Hin + arow * D_ + sc;
    long wrow = (long)e * H_ + nt * 256 + sh * 128 + q * 32 + sr;
    pB[q] = Wdb + wrow * (long)D_ + sc;
  }
  auto SA = [&](int d, int q) { gl16(pA[q], lds + d * 32768 + q * 8192 + ro); pA[q] += 64; };
  auto SB = [&](int d, int q) { gl16(pB[q], lds + 65536 + d * 32768 + q * 8192 + ro); pB[q] += 64; };

  f32x4 acc[8][4] = {};  // [mi][ni]
  short8 BF[4][2], af[2][2];

  SA(0,0); SB(0,0); SA(0,1); SB(0,1); SA(0,2); SB(0,2); SA(0,3); SB(0,3);
  SA(1,0); SB(1,0); SA(1,1); SB(1,1); SA(1,2); SB(1,2);
  asm volatile("s_waitcnt vmcnt(6)" ::: "memory");
  __builtin_amdgcn_s_barrier();

  int rbA = wm * 128 + lrow;
  for (int t = 0; t < NKT; ++t) {
    int d = t & 1;
    const char* Ab = lds + d * 32768;
    const char* Bb = lds + 65536 + d * 32768;

#define G2_MFMA(q)                                                                   \
    __builtin_amdgcn_s_setprio(1);                                                   \
    _Pragma("unroll") for (int m2 = 0; m2 < 2; ++m2)                                 \
      _Pragma("unroll") for (int ks = 0; ks < 2; ++ks)                               \
        _Pragma("unroll") for (int ni = 0; ni < 4; ++ni)                             \
          acc[(q)*2+m2][ni] = __builtin_amdgcn_mfma_f32_16x16x32_bf16(               \
              af[m2][ks], BF[ni][ks], acc[(q)*2+m2][ni], 0, 0, 0);                   \
    __builtin_amdgcn_s_setprio(0);

#define G2_LDA(q)                                                                    \
    _Pragma("unroll") for (int m2 = 0; m2 < 2; ++m2)                                 \
      _Pragma("unroll") for (int ks = 0; ks < 2; ++ks)                               \
        af[m2][ks] = *(const short8*)(Ab + (lds_off(rbA + ((q)*2+m2)*16, ks, lq) ^ X4));

    // phase 0
    #pragma unroll
    for (int ni = 0; ni < 4; ++ni)
      #pragma unroll
      for (int ks = 0; ks < 2; ++ks)
        BF[ni][ks] = *(const short8*)(Bb + (lds_off(wn * 64 + ni * 16 + lrow, ks, lq) ^ X4));
    G2_LDA(0);
    if (t + 1 < NKT) { SA(d ^ 1, 3); SB(d ^ 1, 3); }
    __builtin_amdgcn_s_barrier();
    asm volatile("s_waitcnt lgkmcnt(0)" ::: "memory");
    __builtin_amdgcn_sched_barrier(0);
    G2_MFMA(0);
    __builtin_amdgcn_s_barrier();
    // phase 1
    G2_LDA(1);
    if (t + 2 < NKT) { SA(d, 0); SB(d, 0); }
    __builtin_amdgcn_s_barrier();
    asm volatile("s_waitcnt lgkmcnt(0)" ::: "memory");
    __builtin_amdgcn_sched_barrier(0);
    G2_MFMA(1);
    __builtin_amdgcn_s_barrier();
    // phase 2
    G2_LDA(2);
    if (t + 2 < NKT) { SA(d, 1); SB(d, 1); }
    __builtin_amdgcn_s_barrier();
    asm volatile("s_waitcnt lgkmcnt(0)" ::: "memory");
    __builtin_amdgcn_sched_barrier(0);
    G2_MFMA(2);
    __builtin_amdgcn_s_barrier();
    // phase 3
    G2_LDA(3);
    if (t + 2 < NKT) {
      SA(d, 2); SB(d, 2);
      asm volatile("s_waitcnt vmcnt(6)" ::: "memory");
    } else {
      asm volatile("s_waitcnt vmcnt(0)" ::: "memory");
    }
    __builtin_amdgcn_s_barrier();
    asm volatile("s_waitcnt lgkmcnt(0)" ::: "memory");
    __builtin_amdgcn_sched_barrier(0);
    G2_MFMA(3);
    __builtin_amdgcn_s_barrier();
  }

  // ---- epilogue: LoRA via rank-8 MFMA, direct (row-major) stores
  __syncthreads();
  unsigned short* sLo2 = (unsigned short*)lds;            // [256][32] SCALE*low2
  unsigned short* sB2  = (unsigned short*)(lds + 16384);  // [256][32] Bd rows
  {
    short8 z = {};
    if (tid < 256) {
      const float* lp = low + ((long)e * T_ + mt * 256 + tid) * R_;
      short8 v;
      #pragma unroll
      for (int r = 0; r < 8; ++r) ((unsigned short*)&v)[r] = f2bf(SCALE_ * lp[r]);
      *(short8*)(sLo2 + tid * 32) = v;
      *(short8*)(sLo2 + tid * 32 + 8) = z;
      *(short8*)(sLo2 + tid * 32 + 16) = z;
      *(short8*)(sLo2 + tid * 32 + 24) = z;
    } else {
      int r = tid - 256;
      const float* bp = Bd + ((long)e * H_ + nt * 256 + r) * R_;
      short8 v;
      #pragma unroll
      for (int k = 0; k < 8; ++k) ((unsigned short*)&v)[k] = f2bf(bp[k]);
      *(short8*)(sB2 + r * 32) = v;
      *(short8*)(sB2 + r * 32 + 8) = z;
      *(short8*)(sB2 + r * 32 + 16) = z;
      *(short8*)(sB2 + r * 32 + 24) = z;
    }
  }
  __syncthreads();
  #pragma unroll
  for (int mi = 0; mi < 8; ++mi) {
    short8 alo = *(const short8*)(sLo2 + (rbA + mi * 16) * 32 + lq * 8);
    #pragma unroll
    for (int ni = 0; ni < 4; ++ni) {
      short8 bd2 = *(const short8*)(sB2 + (wn * 64 + ni * 16 + lrow) * 32 + lq * 8);
      acc[mi][ni] = __builtin_amdgcn_mfma_f32_16x16x32_bf16(alo, bd2, acc[mi][ni], 0, 0, 0);
    }
  }
  {
    long rowbase = (long)e * T_ + mt * 256 + wm * 128;
    int colbase = nt * 256 + wn * 64;
    #pragma unroll
    for (int mi = 0; mi < 8; ++mi)
      #pragma unroll
      for (int j = 0; j < 4; ++j) {
        long row = rowbase + mi * 16 + lq * 4 + j;
        #pragma unroll
        for (int ni = 0; ni < 4; ++ni)
          Out[row * H_ + colbase + ni * 16 + lrow] = acc[mi][ni][j];
      }
  }
}

extern "C" void kernel_launch(void* const* d_in, const int* in_sizes, int n_in,
                              void* d_out, int out_size, void* d_ws, size_t ws_size,
                              hipStream_t stream) {
  const float* x   = (const float*)d_in[0];
  const float* Wgu = (const float*)d_in[1];
  const float* Agu = (const float*)d_in[2];
  const float* Bgu = (const float*)d_in[3];
  const float* Wd  = (const float*)d_in[4];
  const float* Ad  = (const float*)d_in[5];
  const float* Bd  = (const float*)d_in[6];
  float* out = (float*)d_out;

  char* ws = (char*)d_ws;
  const size_t SZ_H   = (size_t)E_ * T_ * D_ * 2;        // 128 MiB bf16 h
  const size_t SZ_LOW = (size_t)E_ * T_ * R_ * 4;        // 512 KiB
  const size_t SZ_XB  = (size_t)E_ * T_ * H_ * 2;        // 64 MiB
  const size_t SZ_WGU = (size_t)E_ * TWO_D_ * H_ * 2;    // 256 MiB

  unsigned short* hbuf = (unsigned short*)ws;
  float* low1 = (float*)(ws + SZ_H);
  float* low2 = (float*)(ws + SZ_H + SZ_LOW);
  unsigned short* xb   = (unsigned short*)(ws + SZ_H + 2 * SZ_LOW);
  unsigned short* wgub = (unsigned short*)(ws + SZ_H + 2 * SZ_LOW + SZ_XB);
  unsigned short* wdb  = (unsigned short*)(ws + SZ_H + 2 * SZ_LOW + SZ_XB + SZ_WGU);

  hipLaunchKernelGGL((k_low<H_, false, true>), dim3(E_ * T_ / 4), dim3(256), 0, stream,
                     (const void*)x, Agu, low1, xb);
  hipLaunchKernelGGL(k_f2bf, dim3(2048), dim3(256), 0, stream, Wgu, wgub, (long)E_ * TWO_D_ * H_);
  hipLaunchKernelGGL(k_f2bf, dim3(2048), dim3(256), 0, stream, Wd,  wdb,  (long)E_ * H_ * D_);
  hipLaunchKernelGGL(k_gemm1_8p, dim3(E_ * (T_ / 256) * (D_ / 128)), dim3(512), 0, stream,
                     xb, wgub, Bgu, low1, hbuf);
  hipLaunchKernelGGL((k_low<D_, true, false>), dim3(E_ * T_ / 4), dim3(256), 0, stream,
                     (const void*)hbuf, Ad, low2, (unsigned short*)nullptr);
  hipLaunchKernelGGL(k_gemm2_8p, dim3(E_ * (T_ / 256) * (H_ / 256)), dim3(512), 0, stream,
                     hbuf, wdb, Bd, low2, out);
}

// Round 5
// 1129.289 us; speedup vs baseline: 2.7499x; 1.0344x over previous
//
#include <hip/hip_runtime.h>
#include <hip/hip_bf16.h>

#define E_ 8
#define H_ 2048
#define D_ 4096
#define R_ 8
#define T_ 2048
#define TWO_D_ 8192
#define SCALE_ 2.0f

typedef __attribute__((ext_vector_type(8))) short short8;
typedef __attribute__((ext_vector_type(4))) float f32x4;

__device__ __forceinline__ unsigned short f2bf(float f) {
  union { float f; unsigned u; } c; c.f = f;
  unsigned u = c.u + 0x7fffu + ((c.u >> 16) & 1u);  // RNE
  return (unsigned short)(u >> 16);
}
__device__ __forceinline__ float bf2f(unsigned short s) {
  union { unsigned u; float f; } c; c.u = ((unsigned)s) << 16;
  return c.f;
}

// async 16B global -> LDS (linear dest: wave-uniform base + lane*16)
__device__ __forceinline__ void gl16(const void* g, void* l) {
  __builtin_amdgcn_global_load_lds(
      (const __attribute__((address_space(1))) void*)g,
      (__attribute__((address_space(3))) void*)l, 16, 0, 0);
}

// LDS byte offset inside a 32KB operand region laid out [qtr][half][32 rows][64 cols bf16]
__device__ __forceinline__ int lds_off(int rr, int ks, int lq) {
  return (((rr >> 5) & 3) << 13) | (((rr >> 7) & 1) << 12) | ((rr & 31) << 7) | (ks << 6) | (lq << 4);
}

// ---------------- rank-8 projection (+ optional bf16 copy of input)
template <int K, bool XBF16, bool WRITEXB>
__global__ __launch_bounds__(256) void k_low(const void* __restrict__ Xv,
                                             const float* __restrict__ A,
                                             float* __restrict__ low,
                                             unsigned short* __restrict__ xbout) {
  int wave = (blockIdx.x * 256 + threadIdx.x) >> 6;
  int lane = threadIdx.x & 63;
  int e = wave >> 11;  // / T_
  const float* Ae = A + (long)e * R_ * K;
  float acc[R_] = {0.f,0.f,0.f,0.f,0.f,0.f,0.f,0.f};
  for (int it = 0; it < K / 256; ++it) {
    int i = it * 256 + lane * 4;
    float xv[4];
    if constexpr (!XBF16) {
      const float* x = (const float*)Xv + (long)wave * K;
      f32x4 v = *(const f32x4*)(x + i);
      xv[0]=v[0]; xv[1]=v[1]; xv[2]=v[2]; xv[3]=v[3];
      if constexpr (WRITEXB) {
        ushort4 u; u.x=f2bf(xv[0]); u.y=f2bf(xv[1]); u.z=f2bf(xv[2]); u.w=f2bf(xv[3]);
        *(ushort4*)(xbout + (long)wave * K + i) = u;
      }
    } else {
      const unsigned short* x = (const unsigned short*)Xv + (long)wave * K;
      ushort4 u = *(const ushort4*)(x + i);
      xv[0]=bf2f(u.x); xv[1]=bf2f(u.y); xv[2]=bf2f(u.z); xv[3]=bf2f(u.w);
    }
    #pragma unroll
    for (int r = 0; r < R_; ++r) {
      f32x4 a = *(const f32x4*)(Ae + r * K + i);
      acc[r] += xv[0]*a[0] + xv[1]*a[1] + xv[2]*a[2] + xv[3]*a[3];
    }
  }
  #pragma unroll
  for (int r = 0; r < R_; ++r) {
    float v = acc[r];
    #pragma unroll
    for (int off = 32; off > 0; off >>= 1) v += __shfl_xor(v, off);
    acc[r] = v;
  }
  if (lane == 0) {
    #pragma unroll
    for (int r = 0; r < R_; ++r) low[(long)wave * R_ + r] = acc[r];
  }
}

// ---------------- fp32 -> bf16 bulk conversion
__global__ __launch_bounds__(256) void k_f2bf(const float* __restrict__ src,
                                              unsigned short* __restrict__ dst,
                                              long n) {
  long i = ((long)blockIdx.x * 256 + threadIdx.x) * 8;
  long stride = (long)gridDim.x * 256 * 8;
  for (; i < n; i += stride) {
    f32x4 a = *(const f32x4*)(src + i);
    f32x4 b = *(const f32x4*)(src + i + 4);
    ushort4 lo, hi;
    lo.x=f2bf(a[0]); lo.y=f2bf(a[1]); lo.z=f2bf(a[2]); lo.w=f2bf(a[3]);
    hi.x=f2bf(b[0]); hi.y=f2bf(b[1]); hi.z=f2bf(b[2]); hi.w=f2bf(b[3]);
    *(ushort4*)(dst + i) = lo;
    *(ushort4*)(dst + i + 4) = hi;
  }
}

// ======================= GEMM1: 256x128(gate)+128(up), BK=64, 8-phase =======================
// h = up*silu(gate); gate_up = x@Wgu^T + SCALE*low1@Bgu^T   (LoRA folded as rank-8 MFMA step)
__global__ __launch_bounds__(512, 2) void k_gemm1_8p(
    const unsigned short* __restrict__ Xb, const unsigned short* __restrict__ Wb,
    const float* __restrict__ Bgu, const float* __restrict__ low,
    unsigned short* __restrict__ Hout) {
  __shared__ __align__(16) char lds[131072];  // A: d*32768, B: 65536 + d*32768

  const int MT = T_ / 256, NT = D_ / 128;  // 8, 32
  int b = blockIdx.x;
  int cpx = (int)gridDim.x >> 3;
  int swz = (b & 7) * cpx + (b >> 3);
  int e  = swz / (MT * NT);
  int r0 = swz % (MT * NT);
  int nt = r0 / MT, mt = r0 % MT;

  int tid = threadIdx.x, lane = tid & 63;
  int wid = tid >> 6, wm = wid >> 2, wn = wid & 3;
  int lrow = lane & 15, lq = lane >> 4;
  int X4 = (lrow & 7) << 4;  // 3-row-bit XOR: spreads 16 rows over full 128B row -> 8-cyc b128 floor
  const int NKT = H_ / 64;  // 32

  // ---- staging source pointers (inverse-swizzled global source, linear LDS dest)
  unsigned ro = (unsigned)tid * 16;
  unsigned so = ro ^ (((ro >> 7) & 7u) << 4);
  int sh = (so >> 12) & 1, sr = (so >> 7) & 31, sc = (so & 127) >> 1;
  const unsigned short* pA[4]; const unsigned short* pB[4];
  #pragma unroll
  for (int q = 0; q < 4; ++q) {
    long arow = (long)e * T_ + mt * 256 + sh * 128 + q * 32 + sr;
    pA[q] = Xb + arow * H_ + sc;
    long wrow = sh ? ((long)e * TWO_D_ + D_ + nt * 128 + q * 32 + sr)
                   : ((long)e * TWO_D_ +      nt * 128 + q * 32 + sr);
    pB[q] = Wb + wrow * (long)H_ + sc;
  }
  auto SA = [&](int d, int q) { gl16(pA[q], lds + d * 32768 + q * 8192 + ro); pA[q] += 64; };
  auto SB = [&](int d, int q) { gl16(pB[q], lds + 65536 + d * 32768 + q * 8192 + ro); pB[q] += 64; };

  f32x4 accg[2][8] = {}, accu[2][8] = {};  // [nj][mi]
  short8 BG[2][2], BU[2][2], af[2][2];

  // ---- prologue: tile0 all 8 units, tile1 first 6 units; wait tile0 complete
  SA(0,0); SB(0,0); SA(0,1); SB(0,1); SA(0,2); SB(0,2); SA(0,3); SB(0,3);
  SA(1,0); SB(1,0); SA(1,1); SB(1,1); SA(1,2); SB(1,2);
  asm volatile("s_waitcnt vmcnt(6)" ::: "memory");
  __builtin_amdgcn_s_barrier();

  int rbA = wm * 128 + lrow;
  for (int t = 0; t < NKT; ++t) {
    int d = t & 1;
    const char* Ab = lds + d * 32768;
    const char* Bb = lds + 65536 + d * 32768;

#define G1_MFMA(q)                                                                   \
    __builtin_amdgcn_s_setprio(1);                                                   \
    _Pragma("unroll") for (int m2 = 0; m2 < 2; ++m2)                                 \
      _Pragma("unroll") for (int ks = 0; ks < 2; ++ks)                               \
        _Pragma("unroll") for (int nj = 0; nj < 2; ++nj) {                           \
          accg[nj][(q)*2+m2] = __builtin_amdgcn_mfma_f32_16x16x32_bf16(              \
              BG[nj][ks], af[m2][ks], accg[nj][(q)*2+m2], 0, 0, 0);                  \
          accu[nj][(q)*2+m2] = __builtin_amdgcn_mfma_f32_16x16x32_bf16(              \
              BU[nj][ks], af[m2][ks], accu[nj][(q)*2+m2], 0, 0, 0);                  \
        }                                                                            \
    __builtin_amdgcn_s_setprio(0);

#define G1_LDA(q)                                                                    \
    _Pragma("unroll") for (int m2 = 0; m2 < 2; ++m2)                                 \
      _Pragma("unroll") for (int ks = 0; ks < 2; ++ks)                               \
        af[m2][ks] = *(const short8*)(Ab + (lds_off(rbA + ((q)*2+m2)*16, ks, lq) ^ X4));

#define G1_SYNC()                                                                    \
    __builtin_amdgcn_s_barrier();                                                    \
    asm volatile("s_waitcnt lgkmcnt(0)" ::: "memory");                               \
    __builtin_amdgcn_sched_barrier(0);

    // phase 0: B-frags + A-quad0; stage tile t+1 last units
    #pragma unroll
    for (int nj = 0; nj < 2; ++nj)
      #pragma unroll
      for (int ks = 0; ks < 2; ++ks) {
        int rg = wn * 32 + nj * 16 + lrow;
        BG[nj][ks] = *(const short8*)(Bb + (lds_off(rg, ks, lq) ^ X4));
        BU[nj][ks] = *(const short8*)(Bb + (lds_off(rg + 128, ks, lq) ^ X4));
      }
    G1_LDA(0);
    if (t + 1 < NKT) { SA(d ^ 1, 3); SB(d ^ 1, 3); }
    G1_SYNC();
    G1_MFMA(0);
    __builtin_amdgcn_s_barrier();
    // phase 1
    G1_LDA(1);
    if (t + 2 < NKT) { SA(d, 0); SB(d, 0); }
    G1_SYNC();
    G1_MFMA(1);
    __builtin_amdgcn_s_barrier();
    // phase 2
    G1_LDA(2);
    if (t + 2 < NKT) { SA(d, 1); SB(d, 1); }
    G1_SYNC();
    G1_MFMA(2);
    __builtin_amdgcn_s_barrier();
    // phase 3 (counted vmcnt: 6 loads of tile t+2 may stay in flight)
    G1_LDA(3);
    if (t + 2 < NKT) {
      SA(d, 2); SB(d, 2);
      asm volatile("s_waitcnt vmcnt(6)" ::: "memory");
    } else {
      asm volatile("s_waitcnt vmcnt(0)" ::: "memory");
    }
    G1_SYNC();
    G1_MFMA(3);
    __builtin_amdgcn_s_barrier();
  }

  // ---- epilogue: fold LoRA via one rank-8 (K=32 zero-padded) MFMA step
  __syncthreads();
  unsigned short* sLo2 = (unsigned short*)lds;            // [256][32] bf16: SCALE*low1
  unsigned short* sB2  = (unsigned short*)(lds + 16384);  // [256][32] bf16: Bgu rows (gate|up)
  {
    short8 z = {};
    if (tid < 256) {
      const float* lp = low + ((long)e * T_ + mt * 256 + tid) * R_;
      short8 v;
      #pragma unroll
      for (int r = 0; r < 8; ++r) ((unsigned short*)&v)[r] = f2bf(SCALE_ * lp[r]);
      *(short8*)(sLo2 + tid * 32) = v;
      *(short8*)(sLo2 + tid * 32 + 8) = z;
      *(short8*)(sLo2 + tid * 32 + 16) = z;
      *(short8*)(sLo2 + tid * 32 + 24) = z;
    } else {
      int r = tid - 256;
      long wrow = (r < 128) ? ((long)e * TWO_D_ + nt * 128 + r)
                            : ((long)e * TWO_D_ + D_ + nt * 128 + (r - 128));
      const float* bp = Bgu + wrow * R_;
      short8 v;
      #pragma unroll
      for (int k = 0; k < 8; ++k) ((unsigned short*)&v)[k] = f2bf(bp[k]);
      *(short8*)(sB2 + r * 32) = v;
      *(short8*)(sB2 + r * 32 + 8) = z;
      *(short8*)(sB2 + r * 32 + 16) = z;
      *(short8*)(sB2 + r * 32 + 24) = z;
    }
  }
  __syncthreads();
  {
    #pragma unroll
    for (int mi = 0; mi < 8; ++mi) {
      short8 alo = *(const short8*)(sLo2 + (rbA + mi * 16) * 32 + lq * 8);
      #pragma unroll
      for (int nj = 0; nj < 2; ++nj) {
        int rg = wn * 32 + nj * 16 + lrow;
        short8 bg2 = *(const short8*)(sB2 + rg * 32 + lq * 8);
        short8 bu2 = *(const short8*)(sB2 + (rg + 128) * 32 + lq * 8);
        accg[nj][mi] = __builtin_amdgcn_mfma_f32_16x16x32_bf16(bg2, alo, accg[nj][mi], 0, 0, 0);
        accu[nj][mi] = __builtin_amdgcn_mfma_f32_16x16x32_bf16(bu2, alo, accu[nj][mi], 0, 0, 0);
      }
    }
  }
  // silu + pack -> sT [256][136], then coalesced store
  unsigned short* sT = (unsigned short*)(lds + 32768);
  #pragma unroll
  for (int mi = 0; mi < 8; ++mi) {
    int tl = rbA + mi * 16;
    #pragma unroll
    for (int nj = 0; nj < 2; ++nj) {
      int cb = wn * 32 + nj * 16 + lq * 4;
      ushort4 o;
      #pragma unroll
      for (int j = 0; j < 4; ++j) {
        float gate = accg[nj][mi][j];
        float up   = accu[nj][mi][j];
        float hh = up * (gate / (1.f + __expf(-gate)));
        (&o.x)[j] = f2bf(hh);
      }
      *(ushort4*)(sT + tl * 136 + cb) = o;
    }
  }
  __syncthreads();
  {
    long base = ((long)e * T_ + mt * 256) * D_ + nt * 128;
    int rr2 = tid >> 4, cc2 = (tid & 15) * 8;
    #pragma unroll
    for (int p = 0; p < 8; ++p) {
      int r = p * 32 + rr2;
      short8 v = *(const short8*)(sT + r * 136 + cc2);
      *(short8*)(Hout + base + (long)r * D_ + cc2) = v;
    }
  }
}

// ======================= GEMM2: 256x256, BK=64, 8-phase =======================
// out = h@Wd^T + SCALE*low2@Bd^T (fp32 out; LoRA folded as rank-8 MFMA step)
__global__ __launch_bounds__(512, 2) void k_gemm2_8p(
    const unsigned short* __restrict__ Hin, const unsigned short* __restrict__ Wdb,
    const float* __restrict__ Bd, const float* __restrict__ low,
    float* __restrict__ Out) {
  __shared__ __align__(16) char lds[131072];

  const int MT = T_ / 256, NT = H_ / 256;  // 8, 8
  int b = blockIdx.x;
  int cpx = (int)gridDim.x >> 3;
  int swz = (b & 7) * cpx + (b >> 3);
  int e  = swz / (MT * NT);
  int r0 = swz % (MT * NT);
  int nt = r0 / MT, mt = r0 % MT;

  int tid = threadIdx.x, lane = tid & 63;
  int wid = tid >> 6, wm = wid >> 2, wn = wid & 3;
  int lrow = lane & 15, lq = lane >> 4;
  int X4 = (lrow & 7) << 4;
  const int NKT = D_ / 64;  // 64

  unsigned ro = (unsigned)tid * 16;
  unsigned so = ro ^ (((ro >> 7) & 7u) << 4);
  int sh = (so >> 12) & 1, sr = (so >> 7) & 31, sc = (so & 127) >> 1;
  const unsigned short* pA[4]; const unsigned short* pB[4];
  #pragma unroll
  for (int q = 0; q < 4; ++q) {
    long arow = (long)e * T_ + mt * 256 + sh * 128 + q * 32 + sr;
    pA[q] = Hin + arow * D_ + sc;
    long wrow = (long)e * H_ + nt * 256 + sh * 128 + q * 32 + sr;
    pB[q] = Wdb + wrow * (long)D_ + sc;
  }
  auto SA = [&](int d, int q) { gl16(pA[q], lds + d * 32768 + q * 8192 + ro); pA[q] += 64; };
  auto SB = [&](int d, int q) { gl16(pB[q], lds + 65536 + d * 32768 + q * 8192 + ro); pB[q] += 64; };

  f32x4 acc[8][4] = {};  // [mi][ni]
  short8 BF[4][2], af[2][2];

  SA(0,0); SB(0,0); SA(0,1); SB(0,1); SA(0,2); SB(0,2); SA(0,3); SB(0,3);
  SA(1,0); SB(1,0); SA(1,1); SB(1,1); SA(1,2); SB(1,2);
  asm volatile("s_waitcnt vmcnt(6)" ::: "memory");
  __builtin_amdgcn_s_barrier();

  int rbA = wm * 128 + lrow;
  for (int t = 0; t < NKT; ++t) {
    int d = t & 1;
    const char* Ab = lds + d * 32768;
    const char* Bb = lds + 65536 + d * 32768;

#define G2_MFMA(q)                                                                   \
    __builtin_amdgcn_s_setprio(1);                                                   \
    _Pragma("unroll") for (int m2 = 0; m2 < 2; ++m2)                                 \
      _Pragma("unroll") for (int ks = 0; ks < 2; ++ks)                               \
        _Pragma("unroll") for (int ni = 0; ni < 4; ++ni)                             \
          acc[(q)*2+m2][ni] = __builtin_amdgcn_mfma_f32_16x16x32_bf16(               \
              af[m2][ks], BF[ni][ks], acc[(q)*2+m2][ni], 0, 0, 0);                   \
    __builtin_amdgcn_s_setprio(0);

#define G2_LDA(q)                                                                    \
    _Pragma("unroll") for (int m2 = 0; m2 < 2; ++m2)                                 \
      _Pragma("unroll") for (int ks = 0; ks < 2; ++ks)                               \
        af[m2][ks] = *(const short8*)(Ab + (lds_off(rbA + ((q)*2+m2)*16, ks, lq) ^ X4));

    // phase 0
    #pragma unroll
    for (int ni = 0; ni < 4; ++ni)
      #pragma unroll
      for (int ks = 0; ks < 2; ++ks)
        BF[ni][ks] = *(const short8*)(Bb + (lds_off(wn * 64 + ni * 16 + lrow, ks, lq) ^ X4));
    G2_LDA(0);
    if (t + 1 < NKT) { SA(d ^ 1, 3); SB(d ^ 1, 3); }
    __builtin_amdgcn_s_barrier();
    asm volatile("s_waitcnt lgkmcnt(0)" ::: "memory");
    __builtin_amdgcn_sched_barrier(0);
    G2_MFMA(0);
    __builtin_amdgcn_s_barrier();
    // phase 1
    G2_LDA(1);
    if (t + 2 < NKT) { SA(d, 0); SB(d, 0); }
    __builtin_amdgcn_s_barrier();
    asm volatile("s_waitcnt lgkmcnt(0)" ::: "memory");
    __builtin_amdgcn_sched_barrier(0);
    G2_MFMA(1);
    __builtin_amdgcn_s_barrier();
    // phase 2
    G2_LDA(2);
    if (t + 2 < NKT) { SA(d, 1); SB(d, 1); }
    __builtin_amdgcn_s_barrier();
    asm volatile("s_waitcnt lgkmcnt(0)" ::: "memory");
    __builtin_amdgcn_sched_barrier(0);
    G2_MFMA(2);
    __builtin_amdgcn_s_barrier();
    // phase 3
    G2_LDA(3);
    if (t + 2 < NKT) {
      SA(d, 2); SB(d, 2);
      asm volatile("s_waitcnt vmcnt(6)" ::: "memory");
    } else {
      asm volatile("s_waitcnt vmcnt(0)" ::: "memory");
    }
    __builtin_amdgcn_s_barrier();
    asm volatile("s_waitcnt lgkmcnt(0)" ::: "memory");
    __builtin_amdgcn_sched_barrier(0);
    G2_MFMA(3);
    __builtin_amdgcn_s_barrier();
  }

  // ---- epilogue: LoRA via rank-8 MFMA, direct (row-major) stores
  __syncthreads();
  unsigned short* sLo2 = (unsigned short*)lds;            // [256][32] SCALE*low2
  unsigned short* sB2  = (unsigned short*)(lds + 16384);  // [256][32] Bd rows
  {
    short8 z = {};
    if (tid < 256) {
      const float* lp = low + ((long)e * T_ + mt * 256 + tid) * R_;
      short8 v;
      #pragma unroll
      for (int r = 0; r < 8; ++r) ((unsigned short*)&v)[r] = f2bf(SCALE_ * lp[r]);
      *(short8*)(sLo2 + tid * 32) = v;
      *(short8*)(sLo2 + tid * 32 + 8) = z;
      *(short8*)(sLo2 + tid * 32 + 16) = z;
      *(short8*)(sLo2 + tid * 32 + 24) = z;
    } else {
      int r = tid - 256;
      const float* bp = Bd + ((long)e * H_ + nt * 256 + r) * R_;
      short8 v;
      #pragma unroll
      for (int k = 0; k < 8; ++k) ((unsigned short*)&v)[k] = f2bf(bp[k]);
      *(short8*)(sB2 + r * 32) = v;
      *(short8*)(sB2 + r * 32 + 8) = z;
      *(short8*)(sB2 + r * 32 + 16) = z;
      *(short8*)(sB2 + r * 32 + 24) = z;
    }
  }
  __syncthreads();
  #pragma unroll
  for (int mi = 0; mi < 8; ++mi) {
    short8 alo = *(const short8*)(sLo2 + (rbA + mi * 16) * 32 + lq * 8);
    #pragma unroll
    for (int ni = 0; ni < 4; ++ni) {
      short8 bd2 = *(const short8*)(sB2 + (wn * 64 + ni * 16 + lrow) * 32 + lq * 8);
      acc[mi][ni] = __builtin_amdgcn_mfma_f32_16x16x32_bf16(alo, bd2, acc[mi][ni], 0, 0, 0);
    }
  }
  {
    long rowbase = (long)e * T_ + mt * 256 + wm * 128;
    int colbase = nt * 256 + wn * 64;
    #pragma unroll
    for (int mi = 0; mi < 8; ++mi)
      #pragma unroll
      for (int j = 0; j < 4; ++j) {
        long row = rowbase + mi * 16 + lq * 4 + j;
        #pragma unroll
        for (int ni = 0; ni < 4; ++ni)
          Out[row * H_ + colbase + ni * 16 + lrow] = acc[mi][ni][j];
      }
  }
}

extern "C" void kernel_launch(void* const* d_in, const int* in_sizes, int n_in,
                              void* d_out, int out_size, void* d_ws, size_t ws_size,
                              hipStream_t stream) {
  const float* x   = (const float*)d_in[0];
  const float* Wgu = (const float*)d_in[1];
  const float* Agu = (const float*)d_in[2];
  const float* Bgu = (const float*)d_in[3];
  const float* Wd  = (const float*)d_in[4];
  const float* Ad  = (const float*)d_in[5];
  const float* Bd  = (const float*)d_in[6];
  float* out = (float*)d_out;

  char* ws = (char*)d_ws;
  const size_t SZ_H   = (size_t)E_ * T_ * D_ * 2;        // 128 MiB bf16 h
  const size_t SZ_LOW = (size_t)E_ * T_ * R_ * 4;        // 512 KiB
  const size_t SZ_XB  = (size_t)E_ * T_ * H_ * 2;        // 64 MiB
  const size_t SZ_WGU = (size_t)E_ * TWO_D_ * H_ * 2;    // 256 MiB

  unsigned short* hbuf = (unsigned short*)ws;
  float* low1 = (float*)(ws + SZ_H);
  float* low2 = (float*)(ws + SZ_H + SZ_LOW);
  unsigned short* xb   = (unsigned short*)(ws + SZ_H + 2 * SZ_LOW);
  unsigned short* wgub = (unsigned short*)(ws + SZ_H + 2 * SZ_LOW + SZ_XB);
  unsigned short* wdb  = (unsigned short*)(ws + SZ_H + 2 * SZ_LOW + SZ_XB + SZ_WGU);

  hipLaunchKernelGGL((k_low<H_, false, true>), dim3(E_ * T_ / 4), dim3(256), 0, stream,
                     (const void*)x, Agu, low1, xb);
  hipLaunchKernelGGL(k_f2bf, dim3(2048), dim3(256), 0, stream, Wgu, wgub, (long)E_ * TWO_D_ * H_);
  hipLaunchKernelGGL(k_f2bf, dim3(2048), dim3(256), 0, stream, Wd,  wdb,  (long)E_ * H_ * D_);
  hipLaunchKernelGGL(k_gemm1_8p, dim3(E_ * (T_ / 256) * (D_ / 128)), dim3(512), 0, stream,
                     xb, wgub, Bgu, low1, hbuf);
  hipLaunchKernelGGL((k_low<D_, true, false>), dim3(E_ * T_ / 4), dim3(256), 0, stream,
                     (const void*)hbuf, Ad, low2, (unsigned short*)nullptr);
  hipLaunchKernelGGL(k_gemm2_8p, dim3(E_ * (T_ / 256) * (H_ / 256)), dim3(512), 0, stream,
                     hbuf, wdb, Bd, low2, out);
}